// Round 1
// baseline (212.181 us; speedup 1.0000x reference)
//
#include <hip/hip_runtime.h>

typedef unsigned int u32;
typedef unsigned short u16;
typedef float f32x4 __attribute__((ext_vector_type(4)));
typedef short s16x8 __attribute__((ext_vector_type(8)));

#define Bn 512
#define Sn 512
#define Cn 32
#define Dn 512

// ---------- helpers ----------
__device__ __forceinline__ u32 f2bf(float f) {           // fp32 -> bf16 bits, RNE
  u32 u = __float_as_uint(f);
  return (u + 0x7FFFu + ((u >> 16) & 1u)) >> 16;
}
__device__ __forceinline__ float bfl(u32 p) { return __uint_as_float(p << 16); }
__device__ __forceinline__ float bfh(u32 p) { return __uint_as_float(p & 0xFFFF0000u); }

__device__ __forceinline__ float keyToFloat(u32 k) {     // inverse of order-preserving map
  u32 u = (k & 0x80000000u) ? (k ^ 0x80000000u) : ~k;
  return __uint_as_float(u);
}

// uint-index into swizzled LDS bf16[32][128]: element pair (k even) for (v,k)
__device__ __forceinline__ int xtIdx(int v, int k) {
  return v * 64 + ((((k >> 3) ^ (v & 7))) << 2) + ((k & 7) >> 1);
}

// ---------- kernel 1: gates (top-2 over expert embedding dots; base[b] cancels) ----------
__global__ void k_gates(const float* __restrict__ emb, const float* __restrict__ Wg,
                        float* __restrict__ gbuf) {
  int t = threadIdx.x;
  __shared__ float ed[8];
  if (t < 8) {
    float s = 0.f;
#pragma unroll
    for (int j = 0; j < 32; ++j) s += emb[t * 32 + j] * Wg[Dn + j];
    ed[t] = s;
  }
  __syncthreads();
  if (t == 0) {
    int i1 = 0;
#pragma unroll
    for (int e = 1; e < 8; ++e) if (ed[e] > ed[i1]) i1 = e;
    int i2 = (i1 == 0) ? 1 : 0;
#pragma unroll
    for (int e = 0; e < 8; ++e) if (e != i1 && ed[e] > ed[i2]) i2 = e;
    float a = ed[i1], b = ed[i2];
    float m = fmaxf(a, b);
    float ea = __expf(a - m), eb = __expf(b - m);
    float inv = 1.f / (ea + eb);
    gbuf[0] = ea * inv;
    gbuf[1] = eb * inv;
    ((int*)gbuf)[2] = i1;
    ((int*)gbuf)[3] = i2;
  }
}

// ---------- kernel 2: WmixT[d][s] = bf16(g1*We[e1][s][d] + g2*We[e2][s][d]) ----------
__global__ __launch_bounds__(256) void k_wmix(const float* __restrict__ We,
                                              const float* __restrict__ gbuf,
                                              u16* __restrict__ WmT) {
  __shared__ float tile[64][65];
  int bi = blockIdx.x;                       // 64 blocks: 8 s-tiles x 8 d-tiles
  int sb = (bi & 7) * 64, db = (bi >> 3) * 64;
  float g1 = gbuf[0], g2 = gbuf[1];
  int e1 = ((const int*)gbuf)[2], e2 = ((const int*)gbuf)[3];
  const float* W1 = We + (size_t)e1 * Sn * Dn;
  const float* W2 = We + (size_t)e2 * Sn * Dn;
  int t = threadIdx.x;
#pragma unroll
  for (int i = 0; i < 16; ++i) {
    int idx = t + i * 256;
    int sl = idx >> 6, dl = idx & 63;
    int g = (sb + sl) * Dn + db + dl;
    tile[sl][dl] = g1 * W1[g] + g2 * W2[g];
  }
  __syncthreads();
#pragma unroll
  for (int i = 0; i < 16; ++i) {
    int idx = t + i * 256;
    int dl = idx >> 6, sl = idx & 63;
    WmT[(size_t)(db + dl) * Sn + sb + sl] = (u16)f2bf(tile[sl][dl]);
  }
}

// ---------- kernel 3: colsum[d] = sum_s Wmix_bf16[s][d] ----------
__global__ void k_colsum(const u16* __restrict__ WmT, float* __restrict__ colsum) {
  int d = blockIdx.x, l = threadIdx.x;       // 512 blocks x 64 threads (1 wave)
  const uint4* p = (const uint4*)(WmT + (size_t)d * Sn + l * 8);
  uint4 u = *p;
  float s = bfl(u.x) + bfh(u.x) + bfl(u.y) + bfh(u.y) +
            bfl(u.z) + bfh(u.z) + bfl(u.w) + bfh(u.w);
#pragma unroll
  for (int off = 32; off >= 1; off >>= 1) s += __shfl_xor(s, off, 64);
  if (l == 0) colsum[d] = s;
}

// ---------- kernel 4: exact median per (b,c) via 32-bit bisection on keys ----------
__global__ __launch_bounds__(256) void k_median(const float* __restrict__ x,
                                                float* __restrict__ med) {
  __shared__ float buf[64][36];
  int b = blockIdx.x;
  int t = threadIdx.x;
  int w = t >> 6, l = t & 63;                // wave w handles columns w*8..w*8+7
  u32 K[8][8];                               // K[cc][j]: column c=w*8+cc, element s=j*64+l
  const float4* xb = (const float4*)(x + (size_t)b * Sn * Cn);
#pragma unroll
  for (int sc = 0; sc < 8; ++sc) {
#pragma unroll
    for (int i = 0; i < 2; ++i) {
      int idx = t + i * 256;
      int sl = idx >> 3, vq = idx & 7;
      float4 f = xb[(sc * 64 + sl) * 8 + vq];
      *(float4*)&buf[sl][vq * 4] = f;
    }
    __syncthreads();
#pragma unroll
    for (int cc = 0; cc < 8; ++cc) {
      u32 u = __float_as_uint(buf[l][w * 8 + cc]);
      K[cc][sc] = (u >> 31) ? ~u : (u | 0x80000000u);
    }
    __syncthreads();
  }
  int base = b * 32 + w * 8;
#pragma unroll
  for (int cc = 0; cc < 8; ++cc) {
    u32 a1 = 0;
#pragma unroll
    for (int bit = 31; bit >= 0; --bit) {
      u32 cand = a1 | (1u << bit);
      int c = 0;
#pragma unroll
      for (int j = 0; j < 8; ++j) c += (K[cc][j] < cand) ? 1 : 0;
      c += __shfl_xor(c, 1, 64);  c += __shfl_xor(c, 2, 64);
      c += __shfl_xor(c, 4, 64);  c += __shfl_xor(c, 8, 64);
      c += __shfl_xor(c, 16, 64); c += __shfl_xor(c, 32, 64);
      if (c <= 255) a1 = cand;               // keep largest t with count(<t)<=255
    }
    int cle = 0;
#pragma unroll
    for (int j = 0; j < 8; ++j) cle += (K[cc][j] <= a1) ? 1 : 0;
    cle += __shfl_xor(cle, 1, 64);  cle += __shfl_xor(cle, 2, 64);
    cle += __shfl_xor(cle, 4, 64);  cle += __shfl_xor(cle, 8, 64);
    cle += __shfl_xor(cle, 16, 64); cle += __shfl_xor(cle, 32, 64);
    u32 a2;
    if (cle >= 257) {
      a2 = a1;                               // duplicates span rank 256
    } else {
      u32 mn = 0xFFFFFFFFu;
#pragma unroll
      for (int j = 0; j < 8; ++j) {
        u32 k2 = K[cc][j];
        if (k2 > a1 && k2 < mn) mn = k2;
      }
      mn = min(mn, (u32)__shfl_xor((int)mn, 1, 64));
      mn = min(mn, (u32)__shfl_xor((int)mn, 2, 64));
      mn = min(mn, (u32)__shfl_xor((int)mn, 4, 64));
      mn = min(mn, (u32)__shfl_xor((int)mn, 8, 64));
      mn = min(mn, (u32)__shfl_xor((int)mn, 16, 64));
      mn = min(mn, (u32)__shfl_xor((int)mn, 32, 64));
      a2 = mn;
    }
    if (l == 0) med[base + cc] = 0.5f * (keyToFloat(a1) + keyToFloat(a2));
  }
}

// ---------- kernel 5: out[b][d][v] = sum_s bf16(x[b][s][v])*WmixT[d][s] - med[b][v]*colsum[d]
__global__ __launch_bounds__(256) void k_gemm(const float* __restrict__ x,
                                              const u16* __restrict__ WmT,
                                              const float* __restrict__ med,
                                              const float* __restrict__ colsum,
                                              float* __restrict__ out) {
  __shared__ __align__(16) u32 xT[32 * 128 / 2];  // bf16[32][128], xor-swizzled
  int b = blockIdx.x;
  int t = threadIdx.x;
  int w = t >> 6, l = t & 63;
  int q = l >> 4, col = l & 15;
  int dw = w * 128;                          // wave's 128 d-rows
  f32x4 acc[8][2] = {};
  const float* xb = x + (size_t)b * Sn * Cn;
#pragma unroll 1
  for (int ch = 0; ch < 4; ++ch) {
    int s0 = ch * 128;
    // stage x[b][s0:s0+128][0:32] -> LDS bf16 transposed [v][k]
#pragma unroll
    for (int i = 0; i < 2; ++i) {
      int u = t + i * 256;                   // 0..511
      int sp = u >> 3, vq = u & 7;
      int sl = sp * 2;
      const float4* pa = (const float4*)(xb + (size_t)(s0 + sl) * Cn) + vq;
      float4 fa = pa[0];
      float4 fb = pa[8];                     // next s row
#pragma unroll
      for (int j = 0; j < 4; ++j) {
        int v = vq * 4 + j;
        u32 pk = f2bf((&fa.x)[j]) | (f2bf((&fb.x)[j]) << 16);
        xT[xtIdx(v, sl)] = pk;
      }
    }
    __syncthreads();
#pragma unroll
    for (int kk = 0; kk < 4; ++kk) {
      s16x8 bf[2];
#pragma unroll
      for (int nt = 0; nt < 2; ++nt) {
        int v = col + nt * 16;
        int k = kk * 32 + q * 8;
        bf[nt] = *(const s16x8*)&xT[xtIdx(v, k)];
      }
#pragma unroll
      for (int mt = 0; mt < 8; ++mt) {
        int d = dw + mt * 16 + col;
        const s16x8* ap =
            (const s16x8*)(WmT + (size_t)d * Sn + ch * 128 + kk * 32 + q * 8);
        s16x8 af = *ap;
        acc[mt][0] = __builtin_amdgcn_mfma_f32_16x16x32_bf16(af, bf[0], acc[mt][0], 0, 0, 0);
        acc[mt][1] = __builtin_amdgcn_mfma_f32_16x16x32_bf16(af, bf[1], acc[mt][1], 0, 0, 0);
      }
    }
    __syncthreads();
  }
  float m0 = med[b * 32 + col];
  float m1 = med[b * 32 + 16 + col];
  float* ob = out + (size_t)b * Dn * Cn;
#pragma unroll
  for (int mt = 0; mt < 8; ++mt) {
#pragma unroll
    for (int r = 0; r < 4; ++r) {
      int d = dw + mt * 16 + q * 4 + r;
      float cs = colsum[d];
      ob[d * 32 + col]      = acc[mt][0][r] - m0 * cs;
      ob[d * 32 + 16 + col] = acc[mt][1][r] - m1 * cs;
    }
  }
}

extern "C" void kernel_launch(void* const* d_in, const int* in_sizes, int n_in,
                              void* d_out, int out_size, void* d_ws, size_t ws_size,
                              hipStream_t stream) {
  const float* x   = (const float*)d_in[0];
  const float* emb = (const float*)d_in[3];
  const float* Wg  = (const float*)d_in[4];
  const float* We  = (const float*)d_in[6];
  float* out = (float*)d_out;
  char* ws = (char*)d_ws;
  float* gbuf   = (float*)(ws);              // 16 B
  float* colsum = (float*)(ws + 256);        // 2 KB
  float* med    = (float*)(ws + 4096);       // 64 KB
  u16*   WmT    = (u16*)(ws + 4096 + 65536); // 512 KB

  hipLaunchKernelGGL(k_gates,  dim3(1),   dim3(64),  0, stream, emb, Wg, gbuf);
  hipLaunchKernelGGL(k_wmix,   dim3(64),  dim3(256), 0, stream, We, gbuf, WmT);
  hipLaunchKernelGGL(k_colsum, dim3(512), dim3(64),  0, stream, WmT, colsum);
  hipLaunchKernelGGL(k_median, dim3(512), dim3(256), 0, stream, x, med);
  hipLaunchKernelGGL(k_gemm,   dim3(512), dim3(256), 0, stream, x, WmT, med, colsum, out);
}

// Round 2
// 166.893 us; speedup vs baseline: 1.2714x; 1.2714x over previous
//
#include <hip/hip_runtime.h>

typedef unsigned int u32;
typedef unsigned short u16;
typedef unsigned long long u64;
typedef float f32x4 __attribute__((ext_vector_type(4)));
typedef short s16x8 __attribute__((ext_vector_type(8)));

#define Bn 512
#define Sn 512
#define Cn 32
#define Dn 512

// ---------- helpers ----------
__device__ __forceinline__ u32 f2bf(float f) {           // fp32 -> bf16 bits, RNE
  u32 u = __float_as_uint(f);
  return (u + 0x7FFFu + ((u >> 16) & 1u)) >> 16;
}
__device__ __forceinline__ float bfl(u32 p) { return __uint_as_float(p << 16); }
__device__ __forceinline__ float bfh(u32 p) { return __uint_as_float(p & 0xFFFF0000u); }

__device__ __forceinline__ float keyToFloat(u32 k) {     // inverse of order-preserving map
  u32 u = (k & 0x80000000u) ? (k ^ 0x80000000u) : ~k;
  return __uint_as_float(u);
}

// uint-index into swizzled LDS bf16[32][128]: element pair (k even) for (v,k)
__device__ __forceinline__ int xtIdx(int v, int k) {
  return v * 64 + ((((k >> 3) ^ (v & 7))) << 2) + ((k & 7) >> 1);
}

// ---------- kernel 1: gates (top-2 over expert embedding dots; base[b] cancels) ----------
__global__ void k_gates(const float* __restrict__ emb, const float* __restrict__ Wg,
                        float* __restrict__ gbuf) {
  int t = threadIdx.x;
  __shared__ float ed[8];
  if (t < 8) {
    float s = 0.f;
#pragma unroll
    for (int j = 0; j < 32; ++j) s += emb[t * 32 + j] * Wg[Dn + j];
    ed[t] = s;
  }
  __syncthreads();
  if (t == 0) {
    int i1 = 0;
#pragma unroll
    for (int e = 1; e < 8; ++e) if (ed[e] > ed[i1]) i1 = e;
    int i2 = (i1 == 0) ? 1 : 0;
#pragma unroll
    for (int e = 0; e < 8; ++e) if (e != i1 && ed[e] > ed[i2]) i2 = e;
    float a = ed[i1], b = ed[i2];
    float m = fmaxf(a, b);
    float ea = __expf(a - m), eb = __expf(b - m);
    float inv = 1.f / (ea + eb);
    gbuf[0] = ea * inv;
    gbuf[1] = eb * inv;
    ((int*)gbuf)[2] = i1;
    ((int*)gbuf)[3] = i2;
  }
}

// ---------- kernel 2: WmixT[d][s] = bf16(g1*We[e1][s][d] + g2*We[e2][s][d]) ----------
__global__ __launch_bounds__(256) void k_wmix(const float* __restrict__ We,
                                              const float* __restrict__ gbuf,
                                              u16* __restrict__ WmT) {
  __shared__ float tile[64][65];
  int bi = blockIdx.x;                       // 64 blocks: 8 s-tiles x 8 d-tiles
  int sb = (bi & 7) * 64, db = (bi >> 3) * 64;
  float g1 = gbuf[0], g2 = gbuf[1];
  int e1 = ((const int*)gbuf)[2], e2 = ((const int*)gbuf)[3];
  const float* W1 = We + (size_t)e1 * Sn * Dn;
  const float* W2 = We + (size_t)e2 * Sn * Dn;
  int t = threadIdx.x;
#pragma unroll
  for (int i = 0; i < 16; ++i) {
    int idx = t + i * 256;
    int sl = idx >> 6, dl = idx & 63;
    int g = (sb + sl) * Dn + db + dl;
    tile[sl][dl] = g1 * W1[g] + g2 * W2[g];
  }
  __syncthreads();
#pragma unroll
  for (int i = 0; i < 16; ++i) {
    int idx = t + i * 256;
    int dl = idx >> 6, sl = idx & 63;
    WmT[(size_t)(db + dl) * Sn + sb + sl] = (u16)f2bf(tile[sl][dl]);
  }
}

// ---------- kernel 3: colsum[d] = sum_s Wmix_bf16[s][d] ----------
__global__ void k_colsum(const u16* __restrict__ WmT, float* __restrict__ colsum) {
  int d = blockIdx.x, l = threadIdx.x;       // 512 blocks x 64 threads (1 wave)
  const uint4* p = (const uint4*)(WmT + (size_t)d * Sn + l * 8);
  uint4 u = *p;
  float s = bfl(u.x) + bfh(u.x) + bfl(u.y) + bfh(u.y) +
            bfl(u.z) + bfh(u.z) + bfl(u.w) + bfh(u.w);
#pragma unroll
  for (int off = 32; off >= 1; off >>= 1) s += __shfl_xor(s, off, 64);
  if (l == 0) colsum[d] = s;
}

// ---------- kernel 4: exact median per (b,c) via 32-bit bisection on keys ----------
// Ballot-based counting: v_cmp IS the reduction (64-bit lane mask -> s_bcnt1).
// 1024 blocks: (b, half). Wave w handles columns half*16 + w*4 .. +3.
__global__ __launch_bounds__(256) void k_median(const float* __restrict__ x,
                                                float* __restrict__ med) {
  __shared__ float buf[64][20];              // 64 rows x 16 cols (padded to 20)
  int blk = blockIdx.x;
  int b = blk >> 1, half = blk & 1;
  int t = threadIdx.x;
  int w = t >> 6, l = t & 63;
  u32 K[4][8];                               // K[cc][j]: col = half*16+w*4+cc, s = j*64+l
  const float4* xb = (const float4*)(x + (size_t)b * Sn * Cn);
#pragma unroll
  for (int sc = 0; sc < 8; ++sc) {
    {
      int sl = t >> 2, vq = t & 3;           // 256 threads: 64 rows x 4 float4s (16 cols)
      float4 f = xb[(sc * 64 + sl) * 8 + half * 4 + vq];
      *(float4*)&buf[sl][vq * 4] = f;
    }
    __syncthreads();
#pragma unroll
    for (int cc = 0; cc < 4; ++cc) {
      u32 u = __float_as_uint(buf[l][w * 4 + cc]);
      K[cc][sc] = (u >> 31) ? ~u : (u | 0x80000000u);
    }
    __syncthreads();
  }
  int base = b * 32 + half * 16 + w * 4;
#pragma unroll
  for (int cc = 0; cc < 4; ++cc) {
    u32 a1 = 0;
#pragma unroll
    for (int bit = 31; bit >= 0; --bit) {
      u32 cand = a1 | (1u << bit);
      int c = 0;
#pragma unroll
      for (int j = 0; j < 8; ++j) c += __popcll(__ballot(K[cc][j] < cand));
      if (c <= 255) a1 = cand;               // keep largest t with count(<t)<=255
    }
    int cle = 0;
#pragma unroll
    for (int j = 0; j < 8; ++j) cle += __popcll(__ballot(K[cc][j] <= a1));
    u32 a2;
    if (cle >= 257) {
      a2 = a1;                               // duplicates span rank 256
    } else {
      u32 mn = 0xFFFFFFFFu;
#pragma unroll
      for (int j = 0; j < 8; ++j) {
        u32 k2 = K[cc][j];
        if (k2 > a1 && k2 < mn) mn = k2;
      }
      mn = min(mn, (u32)__shfl_xor((int)mn, 1, 64));
      mn = min(mn, (u32)__shfl_xor((int)mn, 2, 64));
      mn = min(mn, (u32)__shfl_xor((int)mn, 4, 64));
      mn = min(mn, (u32)__shfl_xor((int)mn, 8, 64));
      mn = min(mn, (u32)__shfl_xor((int)mn, 16, 64));
      mn = min(mn, (u32)__shfl_xor((int)mn, 32, 64));
      a2 = mn;
    }
    if (l == 0) med[base + cc] = 0.5f * (keyToFloat(a1) + keyToFloat(a2));
  }
}

// ---------- kernel 5: out[b][d][v] = sum_s bf16(x[b][s][v])*WmixT[d][s] - med[b][v]*colsum[d]
__global__ __launch_bounds__(256) void k_gemm(const float* __restrict__ x,
                                              const u16* __restrict__ WmT,
                                              const float* __restrict__ med,
                                              const float* __restrict__ colsum,
                                              float* __restrict__ out) {
  __shared__ __align__(16) u32 xT[32 * 128 / 2];  // bf16[32][128], xor-swizzled
  int b = blockIdx.x;
  int t = threadIdx.x;
  int w = t >> 6, l = t & 63;
  int q = l >> 4, col = l & 15;
  int dw = w * 128;                          // wave's 128 d-rows
  f32x4 acc[8][2] = {};
  const float* xb = x + (size_t)b * Sn * Cn;
#pragma unroll 1
  for (int ch = 0; ch < 4; ++ch) {
    int s0 = ch * 128;
    // stage x[b][s0:s0+128][0:32] -> LDS bf16 transposed [v][k]
#pragma unroll
    for (int i = 0; i < 2; ++i) {
      int u = t + i * 256;                   // 0..511
      int sp = u >> 3, vq = u & 7;
      int sl = sp * 2;
      const float4* pa = (const float4*)(xb + (size_t)(s0 + sl) * Cn) + vq;
      float4 fa = pa[0];
      float4 fb = pa[8];                     // next s row
#pragma unroll
      for (int j = 0; j < 4; ++j) {
        int v = vq * 4 + j;
        u32 pk = f2bf((&fa.x)[j]) | (f2bf((&fb.x)[j]) << 16);
        xT[xtIdx(v, sl)] = pk;
      }
    }
    __syncthreads();
#pragma unroll
    for (int kk = 0; kk < 4; ++kk) {
      s16x8 bf[2];
#pragma unroll
      for (int nt = 0; nt < 2; ++nt) {
        int v = col + nt * 16;
        int k = kk * 32 + q * 8;
        bf[nt] = *(const s16x8*)&xT[xtIdx(v, k)];
      }
#pragma unroll
      for (int mt = 0; mt < 8; ++mt) {
        int d = dw + mt * 16 + col;
        const s16x8* ap =
            (const s16x8*)(WmT + (size_t)d * Sn + ch * 128 + kk * 32 + q * 8);
        s16x8 af = *ap;
        acc[mt][0] = __builtin_amdgcn_mfma_f32_16x16x32_bf16(af, bf[0], acc[mt][0], 0, 0, 0);
        acc[mt][1] = __builtin_amdgcn_mfma_f32_16x16x32_bf16(af, bf[1], acc[mt][1], 0, 0, 0);
      }
    }
    __syncthreads();
  }
  float m0 = med[b * 32 + col];
  float m1 = med[b * 32 + 16 + col];
  float* ob = out + (size_t)b * Dn * Cn;
#pragma unroll
  for (int mt = 0; mt < 8; ++mt) {
#pragma unroll
    for (int r = 0; r < 4; ++r) {
      int d = dw + mt * 16 + q * 4 + r;
      float cs = colsum[d];
      ob[d * 32 + col]      = acc[mt][0][r] - m0 * cs;
      ob[d * 32 + 16 + col] = acc[mt][1][r] - m1 * cs;
    }
  }
}

extern "C" void kernel_launch(void* const* d_in, const int* in_sizes, int n_in,
                              void* d_out, int out_size, void* d_ws, size_t ws_size,
                              hipStream_t stream) {
  const float* x   = (const float*)d_in[0];
  const float* emb = (const float*)d_in[3];
  const float* Wg  = (const float*)d_in[4];
  const float* We  = (const float*)d_in[6];
  float* out = (float*)d_out;
  char* ws = (char*)d_ws;
  float* gbuf   = (float*)(ws);              // 16 B
  float* colsum = (float*)(ws + 256);        // 2 KB
  float* med    = (float*)(ws + 4096);       // 64 KB
  u16*   WmT    = (u16*)(ws + 4096 + 65536); // 512 KB

  hipLaunchKernelGGL(k_gates,  dim3(1),    dim3(64),  0, stream, emb, Wg, gbuf);
  hipLaunchKernelGGL(k_wmix,   dim3(64),   dim3(256), 0, stream, We, gbuf, WmT);
  hipLaunchKernelGGL(k_colsum, dim3(512),  dim3(64),  0, stream, WmT, colsum);
  hipLaunchKernelGGL(k_median, dim3(1024), dim3(256), 0, stream, x, med);
  hipLaunchKernelGGL(k_gemm,   dim3(512),  dim3(256), 0, stream, x, WmT, med, colsum, out);
}

// Round 3
// 148.401 us; speedup vs baseline: 1.4298x; 1.1246x over previous
//
#include <hip/hip_runtime.h>

typedef unsigned int u32;
typedef unsigned short u16;
typedef float f32x4 __attribute__((ext_vector_type(4)));
typedef short s16x8 __attribute__((ext_vector_type(8)));

#define Bn 512
#define Sn 512
#define Cn 32
#define Dn 512

// ---------- helpers ----------
__device__ __forceinline__ u32 f2bf(float f) {           // fp32 -> bf16 bits, RNE
  u32 u = __float_as_uint(f);
  return (u + 0x7FFFu + ((u >> 16) & 1u)) >> 16;
}
__device__ __forceinline__ float bfl(u32 p) { return __uint_as_float(p << 16); }
__device__ __forceinline__ float bfh(u32 p) { return __uint_as_float(p & 0xFFFF0000u); }
__device__ __forceinline__ float keyToFloat(u32 k) {     // inverse of order-preserving map
  u32 u = (k & 0x80000000u) ? (k ^ 0x80000000u) : ~k;
  return __uint_as_float(u);
}
// async 16B global->LDS (LDS side must be wave-uniform base + lane*16)
__device__ __forceinline__ void gl2lds16(const void* g, void* l) {
  __builtin_amdgcn_global_load_lds(
      (const __attribute__((address_space(1))) u32*)g,
      (__attribute__((address_space(3))) u32*)l, 16, 0, 0);
}

// ---------- kernel 1: gates (top-2 over expert embedding dots; base[b] cancels) ----------
__global__ void k_gates(const float* __restrict__ emb, const float* __restrict__ Wg,
                        float* __restrict__ gbuf) {
  int t = threadIdx.x;
  __shared__ float ed[8];
  if (t < 8) {
    float s = 0.f;
#pragma unroll
    for (int j = 0; j < 32; ++j) s += emb[t * 32 + j] * Wg[Dn + j];
    ed[t] = s;
  }
  __syncthreads();
  if (t == 0) {
    int i1 = 0;
#pragma unroll
    for (int e = 1; e < 8; ++e) if (ed[e] > ed[i1]) i1 = e;
    int i2 = (i1 == 0) ? 1 : 0;
#pragma unroll
    for (int e = 0; e < 8; ++e) if (e != i1 && ed[e] > ed[i2]) i2 = e;
    float a = ed[i1], b = ed[i2];
    float m = fmaxf(a, b);
    float ea = __expf(a - m), eb = __expf(b - m);
    float inv = 1.f / (ea + eb);
    gbuf[0] = ea * inv;
    gbuf[1] = eb * inv;
    ((int*)gbuf)[2] = i1;
    ((int*)gbuf)[3] = i2;
  }
}

// ---------- kernel 2: WmixT[d][s] = bf16(g1*We[e1][s][d] + g2*We[e2][s][d]) ----------
__global__ __launch_bounds__(256) void k_wmix(const float* __restrict__ We,
                                              const float* __restrict__ gbuf,
                                              u16* __restrict__ WmT) {
  __shared__ float tile[64][65];
  int bi = blockIdx.x;                       // 64 blocks: 8 s-tiles x 8 d-tiles
  int sb = (bi & 7) * 64, db = (bi >> 3) * 64;
  float g1 = gbuf[0], g2 = gbuf[1];
  int e1 = ((const int*)gbuf)[2], e2 = ((const int*)gbuf)[3];
  const float* W1 = We + (size_t)e1 * Sn * Dn;
  const float* W2 = We + (size_t)e2 * Sn * Dn;
  int t = threadIdx.x;
#pragma unroll
  for (int i = 0; i < 16; ++i) {
    int idx = t + i * 256;
    int sl = idx >> 6, dl = idx & 63;
    int g = (sb + sl) * Dn + db + dl;
    tile[sl][dl] = g1 * W1[g] + g2 * W2[g];
  }
  __syncthreads();
#pragma unroll
  for (int i = 0; i < 16; ++i) {
    int idx = t + i * 256;
    int dl = idx >> 6, sl = idx & 63;
    WmT[(size_t)(db + dl) * Sn + sb + sl] = (u16)f2bf(tile[sl][dl]);
  }
}

// ---------- kernel 3: colsum[d] = sum_s Wmix_bf16[s][d] ----------
__global__ void k_colsum(const u16* __restrict__ WmT, float* __restrict__ colsum) {
  int d = blockIdx.x, l = threadIdx.x;       // 512 blocks x 64 threads (1 wave)
  const uint4* p = (const uint4*)(WmT + (size_t)d * Sn + l * 8);
  uint4 u = *p;
  float s = bfl(u.x) + bfh(u.x) + bfl(u.y) + bfh(u.y) +
            bfl(u.z) + bfh(u.z) + bfl(u.w) + bfh(u.w);
#pragma unroll
  for (int off = 32; off >= 1; off >>= 1) s += __shfl_xor(s, off, 64);
  if (l == 0) colsum[d] = s;
}

// ---------- kernel 4: median (exact, ballot bisection) + write xbf[b*32+v][s] bf16 ----------
// 1024 blocks (b, half). Single barrier; all global loads pipelined up front.
__global__ __launch_bounds__(256) void k_prep(const float* __restrict__ x,
                                              float* __restrict__ med,
                                              u16* __restrict__ xbf) {
  __shared__ float buf[512][17];             // pad 17: phase-2/3 reads ~conflict-free
  int blk = blockIdx.x;
  int b = blk >> 1, half = blk & 1;
  int vbase = half * 16;
  int t = threadIdx.x;
  int w = t >> 6, l = t & 63;
  const float4* xb4 = (const float4*)(x + (size_t)b * Sn * Cn);
  // phase 1: load 512 s x 16 v, all loads issued back-to-back
  float4 f[8];
#pragma unroll
  for (int i = 0; i < 8; ++i)
    f[i] = xb4[((t >> 2) + i * 64) * 8 + half * 4 + (t & 3)];
#pragma unroll
  for (int i = 0; i < 8; ++i) {
    int s = (t >> 2) + i * 64, c0 = (t & 3) * 4;
    buf[s][c0 + 0] = f[i].x; buf[s][c0 + 1] = f[i].y;
    buf[s][c0 + 2] = f[i].z; buf[s][c0 + 3] = f[i].w;
  }
  __syncthreads();
  // phase 2: per-wave keys for columns w*4..w*4+3
  u32 K[4][8];
#pragma unroll
  for (int cc = 0; cc < 4; ++cc)
#pragma unroll
    for (int j = 0; j < 8; ++j) {
      u32 u = __float_as_uint(buf[j * 64 + l][w * 4 + cc]);
      K[cc][j] = (u >> 31) ? ~u : (u | 0x80000000u);
    }
  // phase 3: transposed bf16 write (overlaps bisection's ALU)
  {
    int vl = t >> 4, sb = (t & 15) * 32;
    u16* orow = xbf + ((size_t)(b * 32 + vbase + vl)) * Sn;
#pragma unroll
    for (int cq = 0; cq < 4; ++cq) {
      int cp = (cq + (t & 15)) & 3;          // chunk rotation vs bank conflicts
      u32 pk[4];
#pragma unroll
      for (int jj = 0; jj < 4; ++jj) {
        u32 lo = f2bf(buf[sb + cp * 8 + jj * 2][vl]);
        u32 hi = f2bf(buf[sb + cp * 8 + jj * 2 + 1][vl]);
        pk[jj] = lo | (hi << 16);
      }
      *(uint4*)(orow + sb + cp * 8) = *(uint4*)pk;
    }
  }
  // phase 4: bisection for rank-255/256 mean
  int base = b * 32 + vbase + w * 4;
#pragma unroll
  for (int cc = 0; cc < 4; ++cc) {
    u32 a1 = 0;
#pragma unroll
    for (int bit = 31; bit >= 0; --bit) {
      u32 cand = a1 | (1u << bit);
      int c = 0;
#pragma unroll
      for (int j = 0; j < 8; ++j) c += __popcll(__ballot(K[cc][j] < cand));
      if (c <= 255) a1 = cand;
    }
    int cle = 0;
#pragma unroll
    for (int j = 0; j < 8; ++j) cle += __popcll(__ballot(K[cc][j] <= a1));
    u32 a2;
    if (cle >= 257) {
      a2 = a1;
    } else {
      u32 mn = 0xFFFFFFFFu;
#pragma unroll
      for (int j = 0; j < 8; ++j) {
        u32 k2 = K[cc][j];
        if (k2 > a1 && k2 < mn) mn = k2;
      }
      mn = min(mn, (u32)__shfl_xor((int)mn, 1, 64));
      mn = min(mn, (u32)__shfl_xor((int)mn, 2, 64));
      mn = min(mn, (u32)__shfl_xor((int)mn, 4, 64));
      mn = min(mn, (u32)__shfl_xor((int)mn, 8, 64));
      mn = min(mn, (u32)__shfl_xor((int)mn, 16, 64));
      mn = min(mn, (u32)__shfl_xor((int)mn, 32, 64));
      a2 = mn;
    }
    if (l == 0) med[base + cc] = 0.5f * (keyToFloat(a1) + keyToFloat(a2));
  }
}

// ---------- kernel 5: GEMM  out[b][d][v] = sum_s WmT[d][s]*xbf[b*32+v][s] - med*colsum ----
// M=512 (d), N=16384 (b*32+v), K=512 (s). 128x128 tiles, BK=64, 4 waves.
__global__ __launch_bounds__(256) void k_gemm(const u16* __restrict__ WmT,
                                              const u16* __restrict__ xbf,
                                              const float* __restrict__ med,
                                              const float* __restrict__ colsum,
                                              float* __restrict__ out) {
  __shared__ __align__(16) u16 As[128 * 64]; // [m][k], 128B rows, 16B chunks XOR-swizzled
  __shared__ __align__(16) u16 Bs[128 * 64]; // [n][k], same
  int bi = blockIdx.x;
  int mb = bi & 3, nb = bi >> 2;             // nb-major: consecutive blocks share B rows
  int t = threadIdx.x, w = t >> 6, l = t & 63;
  int mh = (w & 1) * 64, nh = (w >> 1) * 64;
  int lane16 = l & 15, q = l >> 4;
  f32x4 acc[4][4] = {};
  int r0 = t >> 3, c = t & 7;
  const u16* Ab = WmT + (size_t)(mb * 128) * Sn;
  const u16* Bb = xbf + (size_t)(nb * 128) * Sn;
#pragma unroll 1
  for (int ch = 0; ch < 8; ++ch) {
    int k0 = ch * 64;
    // stage A and B: 4+4 async 16B loads per thread, XOR swizzle on GLOBAL chunk
#pragma unroll
    for (int i = 0; i < 4; ++i) {
      int r = r0 + i * 32;
      int gc = c ^ (r & 7);
      gl2lds16(Ab + (size_t)r * Sn + k0 + gc * 8, (char*)As + t * 16 + i * 4096);
      gl2lds16(Bb + (size_t)r * Sn + k0 + gc * 8, (char*)Bs + t * 16 + i * 4096);
    }
    __syncthreads();
#pragma unroll
    for (int kk = 0; kk < 2; ++kk) {
      s16x8 af[4], bf[4];
#pragma unroll
      for (int mt = 0; mt < 4; ++mt) {
        int m = mh + mt * 16 + lane16;
        int cs = (kk * 4 + q) ^ (m & 7);
        af[mt] = *(const s16x8*)(As + m * 64 + cs * 8);
      }
#pragma unroll
      for (int nt = 0; nt < 4; ++nt) {
        int n = nh + nt * 16 + lane16;
        int cs = (kk * 4 + q) ^ (n & 7);
        bf[nt] = *(const s16x8*)(Bs + n * 64 + cs * 8);
      }
#pragma unroll
      for (int mt = 0; mt < 4; ++mt)
#pragma unroll
        for (int nt = 0; nt < 4; ++nt)
          acc[mt][nt] = __builtin_amdgcn_mfma_f32_16x16x32_bf16(af[mt], bf[nt], acc[mt][nt], 0, 0, 0);
    }
    __syncthreads();
  }
  // epilogue: subtract med[n]*colsum[d]
#pragma unroll
  for (int nt = 0; nt < 4; ++nt) {
    int n = nb * 128 + nh + nt * 16 + lane16;
    int b = n >> 5, v = n & 31;
    float mv = med[n];
    float* obase = out + (size_t)b * (Dn * Cn) + v;
#pragma unroll
    for (int mt = 0; mt < 4; ++mt) {
      int d0 = mb * 128 + mh + mt * 16 + q * 4;
      f32x4 cs = *(const f32x4*)(colsum + d0);
#pragma unroll
      for (int r = 0; r < 4; ++r)
        obase[(size_t)(d0 + r) * Cn] = acc[mt][nt][r] - mv * cs[r];
    }
  }
}

extern "C" void kernel_launch(void* const* d_in, const int* in_sizes, int n_in,
                              void* d_out, int out_size, void* d_ws, size_t ws_size,
                              hipStream_t stream) {
  const float* x   = (const float*)d_in[0];
  const float* emb = (const float*)d_in[3];
  const float* Wg  = (const float*)d_in[4];
  const float* We  = (const float*)d_in[6];
  float* out = (float*)d_out;
  char* ws = (char*)d_ws;
  float* gbuf   = (float*)(ws);                        // 16 B
  float* colsum = (float*)(ws + 256);                  // 2 KB
  float* med    = (float*)(ws + 4096);                 // 64 KB
  u16*   WmT    = (u16*)(ws + 4096 + 65536);           // 512 KB
  u16*   xbf    = (u16*)(ws + 4096 + 65536 + 524288);  // 16.8 MB

  hipLaunchKernelGGL(k_gates,  dim3(1),    dim3(64),  0, stream, emb, Wg, gbuf);
  hipLaunchKernelGGL(k_wmix,   dim3(64),   dim3(256), 0, stream, We, gbuf, WmT);
  hipLaunchKernelGGL(k_colsum, dim3(512),  dim3(64),  0, stream, WmT, colsum);
  hipLaunchKernelGGL(k_prep,   dim3(1024), dim3(256), 0, stream, x, med, xbf);
  hipLaunchKernelGGL(k_gemm,   dim3(512),  dim3(256), 0, stream, WmT, xbf, med, colsum, out);
}

// Round 5
// 141.271 us; speedup vs baseline: 1.5019x; 1.0505x over previous
//
#include <hip/hip_runtime.h>

typedef unsigned int u32;
typedef unsigned short u16;
typedef float f32x4 __attribute__((ext_vector_type(4)));
typedef short s16x8 __attribute__((ext_vector_type(8)));

#define Bn 512
#define Sn 512
#define Cn 32
#define Dn 512

// ---------- helpers ----------
__device__ __forceinline__ u32 f2bf(float f) {           // fp32 -> bf16 bits, RNE
  u32 u = __float_as_uint(f);
  return (u + 0x7FFFu + ((u >> 16) & 1u)) >> 16;
}
__device__ __forceinline__ float bfval(u32 bits) { return __uint_as_float(bits << 16); }
__device__ __forceinline__ float keyToFloat(u32 k) {     // inverse of order-preserving map
  u32 u = (k & 0x80000000u) ? (k ^ 0x80000000u) : ~k;
  return __uint_as_float(u);
}
// async 16B global->LDS (LDS side must be wave-uniform base + lane*16)
__device__ __forceinline__ void gl2lds16(const void* g, void* l) {
  __builtin_amdgcn_global_load_lds(
      (const __attribute__((address_space(1))) u32*)g,
      (__attribute__((address_space(3))) u32*)l, 16, 0, 0);
}

// ---------- kernel 1: fused prep (blocks 0..1023) + wmix/gates/colsum (blocks 1024..1087)
// prep: exact median per (b,c) via ballot bisection + write xbf[b*32+v][s] bf16
// wmix: WmixT[d][s] = bf16(g1*We[e1][s][d] + g2*We[e2][s][d]), partial colsums
__global__ __launch_bounds__(256) void k_pw(const float* __restrict__ x,
                                            const float* __restrict__ emb,
                                            const float* __restrict__ Wg,
                                            const float* __restrict__ We,
                                            float* __restrict__ med,
                                            u16* __restrict__ xbf,
                                            u16* __restrict__ WmT,
                                            float* __restrict__ cpart) {
  __shared__ float buf[512][17];             // prep view; wmix aliases first 16.6 KB
  __shared__ float ed[8];
  int blk = blockIdx.x;
  int t = threadIdx.x;

  if (blk < 1024) {
    // ================= prep path =================
    int b = blk >> 1, half = blk & 1;
    int vbase = half * 16;
    int w = t >> 6, l = t & 63;
    const float4* xb4 = (const float4*)(x + (size_t)b * Sn * Cn);
    // phase 1: load 512 s x 16 v, all loads issued back-to-back
    float4 f[8];
#pragma unroll
    for (int i = 0; i < 8; ++i)
      f[i] = xb4[((t >> 2) + i * 64) * 8 + half * 4 + (t & 3)];
#pragma unroll
    for (int i = 0; i < 8; ++i) {
      int s = (t >> 2) + i * 64, c0 = (t & 3) * 4;
      buf[s][c0 + 0] = f[i].x; buf[s][c0 + 1] = f[i].y;
      buf[s][c0 + 2] = f[i].z; buf[s][c0 + 3] = f[i].w;
    }
    __syncthreads();
    // phase 2: per-wave keys for columns w*4..w*4+3
    u32 K[4][8];
#pragma unroll
    for (int cc = 0; cc < 4; ++cc)
#pragma unroll
      for (int j = 0; j < 8; ++j) {
        u32 u = __float_as_uint(buf[j * 64 + l][w * 4 + cc]);
        K[cc][j] = (u >> 31) ? ~u : (u | 0x80000000u);
      }
    // phase 3: transposed bf16 write (overlaps bisection's ALU)
    {
      int vl = t >> 4, sb = (t & 15) * 32;
      u16* orow = xbf + ((size_t)(b * 32 + vbase + vl)) * Sn;
#pragma unroll
      for (int cq = 0; cq < 4; ++cq) {
        int cp = (cq + (t & 15)) & 3;        // chunk rotation vs bank conflicts
        u32 pk[4];
#pragma unroll
        for (int jj = 0; jj < 4; ++jj) {
          u32 lo = f2bf(buf[sb + cp * 8 + jj * 2][vl]);
          u32 hi = f2bf(buf[sb + cp * 8 + jj * 2 + 1][vl]);
          pk[jj] = lo | (hi << 16);
        }
        *(uint4*)(orow + sb + cp * 8) = *(uint4*)pk;
      }
    }
    // phase 4: bisection for rank-255/256 mean
    int base = b * 32 + vbase + w * 4;
#pragma unroll
    for (int cc = 0; cc < 4; ++cc) {
      u32 a1 = 0;
#pragma unroll
      for (int bit = 31; bit >= 0; --bit) {
        u32 cand = a1 | (1u << bit);
        int c = 0;
#pragma unroll
        for (int j = 0; j < 8; ++j) c += __popcll(__ballot(K[cc][j] < cand));
        if (c <= 255) a1 = cand;
      }
      int cle = 0;
#pragma unroll
      for (int j = 0; j < 8; ++j) cle += __popcll(__ballot(K[cc][j] <= a1));
      u32 a2;
      if (cle >= 257) {
        a2 = a1;
      } else {
        u32 mn = 0xFFFFFFFFu;
#pragma unroll
        for (int j = 0; j < 8; ++j) {
          u32 k2 = K[cc][j];
          if (k2 > a1 && k2 < mn) mn = k2;
        }
        mn = min(mn, (u32)__shfl_xor((int)mn, 1, 64));
        mn = min(mn, (u32)__shfl_xor((int)mn, 2, 64));
        mn = min(mn, (u32)__shfl_xor((int)mn, 4, 64));
        mn = min(mn, (u32)__shfl_xor((int)mn, 8, 64));
        mn = min(mn, (u32)__shfl_xor((int)mn, 16, 64));
        mn = min(mn, (u32)__shfl_xor((int)mn, 32, 64));
        a2 = mn;
      }
      if (l == 0) med[base + cc] = 0.5f * (keyToFloat(a1) + keyToFloat(a2));
    }
  } else {
    // ================= wmix path =================
    float (*tile)[65] = (float(*)[65])&buf[0][0];   // 64x65 alias
    int bi2 = blk - 1024;                    // 64 blocks: 8 s-tiles x 8 d-tiles
    int si = bi2 & 7, sb = si * 64, db = (bi2 >> 3) * 64;
    // gates: redundant per block
    if (t < 8) {
      float s = 0.f;
#pragma unroll
      for (int j = 0; j < 32; ++j) s += emb[t * 32 + j] * Wg[Dn + j];
      ed[t] = s;
    }
    __syncthreads();
    int i1 = 0;
#pragma unroll
    for (int e = 1; e < 8; ++e) if (ed[e] > ed[i1]) i1 = e;
    int i2 = (i1 == 0) ? 1 : 0;
#pragma unroll
    for (int e = 0; e < 8; ++e) if (e != i1 && ed[e] > ed[i2]) i2 = e;
    float aa = ed[i1], bb = ed[i2];
    float m = fmaxf(aa, bb);
    float ea = __expf(aa - m), eb = __expf(bb - m);
    float inv = 1.f / (ea + eb);
    float g1 = ea * inv, g2 = eb * inv;
    const float* W1 = We + (size_t)i1 * Sn * Dn;
    const float* W2 = We + (size_t)i2 * Sn * Dn;
#pragma unroll
    for (int i = 0; i < 16; ++i) {
      int idx = t + i * 256;
      int sl = idx >> 6, dl = idx & 63;
      int g = (sb + sl) * Dn + db + dl;
      tile[sl][dl] = g1 * W1[g] + g2 * W2[g];
    }
    __syncthreads();
#pragma unroll
    for (int i = 0; i < 16; ++i) {
      int idx = t + i * 256;
      int dl = idx >> 6, sl = idx & 63;
      WmT[(size_t)(db + dl) * Sn + sb + sl] = (u16)f2bf(tile[sl][dl]);
    }
    // partial colsum over this s-tile: 4 threads per d
    {
      int dl = t >> 2, part = t & 3;
      float s = 0.f;
#pragma unroll
      for (int j = 0; j < 16; ++j)
        s += bfval(f2bf(tile[part * 16 + j][dl]));
      s += __shfl_xor(s, 1, 64);
      s += __shfl_xor(s, 2, 64);
      if (part == 0) cpart[si * 512 + db + dl] = s;
    }
  }
}

// ---------- kernel 2: GEMM  out[b][d][v] = sum_s WmT[d][s]*xbf[b*32+v][s] - med*colsum ----
// M=512 (d), N=16384 (b*32+v), K=512 (s). 128x128 tiles, BK=64, 4 waves.
__global__ __launch_bounds__(256) void k_gemm(const u16* __restrict__ WmT,
                                              const u16* __restrict__ xbf,
                                              const float* __restrict__ med,
                                              const float* __restrict__ cpart,
                                              float* __restrict__ out) {
  __shared__ __align__(16) u16 As[128 * 64]; // [m][k], 128B rows, 16B chunks XOR-swizzled
  __shared__ __align__(16) u16 Bs[128 * 64]; // [n][k], same
  __shared__ float csum[512];
  int bi = blockIdx.x;
  int mb = bi & 3, nb = bi >> 2;             // nb-major: consecutive blocks share B rows
  int t = threadIdx.x, w = t >> 6, l = t & 63;
  int mh = (w & 1) * 64, nh = (w >> 1) * 64;
  int lane16 = l & 15, q = l >> 4;
  // reduce colsum partials into LDS (visible after first in-loop barrier)
#pragma unroll
  for (int d = t; d < 512; d += 256) {
    float s = 0.f;
#pragma unroll
    for (int j = 0; j < 8; ++j) s += cpart[j * 512 + d];
    csum[d] = s;
  }
  f32x4 acc[4][4] = {};
  int r0 = t >> 3, c = t & 7;
  const u16* Ab = WmT + (size_t)(mb * 128) * Sn;
  const u16* Bb = xbf + (size_t)(nb * 128) * Sn;
#pragma unroll 1
  for (int ch = 0; ch < 8; ++ch) {
    int k0 = ch * 64;
    // stage A and B: 4+4 async 16B loads per thread, XOR swizzle on GLOBAL chunk
#pragma unroll
    for (int i = 0; i < 4; ++i) {
      int r = r0 + i * 32;
      int gc = c ^ (r & 7);
      gl2lds16(Ab + (size_t)r * Sn + k0 + gc * 8, (char*)As + t * 16 + i * 4096);
      gl2lds16(Bb + (size_t)r * Sn + k0 + gc * 8, (char*)Bs + t * 16 + i * 4096);
    }
    __syncthreads();
#pragma unroll
    for (int kk = 0; kk < 2; ++kk) {
      s16x8 af[4], bf[4];
#pragma unroll
      for (int mt = 0; mt < 4; ++mt) {
        int m = mh + mt * 16 + lane16;
        int cs = (kk * 4 + q) ^ (m & 7);
        af[mt] = *(const s16x8*)(As + m * 64 + cs * 8);
      }
#pragma unroll
      for (int nt = 0; nt < 4; ++nt) {
        int n = nh + nt * 16 + lane16;
        int cs = (kk * 4 + q) ^ (n & 7);
        bf[nt] = *(const s16x8*)(Bs + n * 64 + cs * 8);
      }
#pragma unroll
      for (int mt = 0; mt < 4; ++mt)
#pragma unroll
        for (int nt = 0; nt < 4; ++nt)
          acc[mt][nt] = __builtin_amdgcn_mfma_f32_16x16x32_bf16(af[mt], bf[nt], acc[mt][nt], 0, 0, 0);
    }
    __syncthreads();
  }
  // epilogue: subtract med[n]*colsum[d]
#pragma unroll
  for (int nt = 0; nt < 4; ++nt) {
    int n = nb * 128 + nh + nt * 16 + lane16;
    int b = n >> 5, v = n & 31;
    float mv = med[n];
    float* obase = out + (size_t)b * (Dn * Cn) + v;
#pragma unroll
    for (int mt = 0; mt < 4; ++mt) {
      int d0 = mb * 128 + mh + mt * 16 + q * 4;
#pragma unroll
      for (int r = 0; r < 4; ++r)
        obase[(size_t)(d0 + r) * Cn] = acc[mt][nt][r] - mv * csum[d0 + r];
    }
  }
}

extern "C" void kernel_launch(void* const* d_in, const int* in_sizes, int n_in,
                              void* d_out, int out_size, void* d_ws, size_t ws_size,
                              hipStream_t stream) {
  const float* x   = (const float*)d_in[0];
  const float* emb = (const float*)d_in[3];
  const float* Wg  = (const float*)d_in[4];
  const float* We  = (const float*)d_in[6];
  float* out = (float*)d_out;
  char* ws = (char*)d_ws;
  float* med   = (float*)(ws);                         // 64 KB
  float* cpart = (float*)(ws + 65536);                 // 16 KB
  u16*   WmT   = (u16*)(ws + 65536 + 16384);           // 512 KB
  u16*   xbf   = (u16*)(ws + 65536 + 16384 + 524288);  // 16.8 MB

  hipLaunchKernelGGL(k_pw,   dim3(1088), dim3(256), 0, stream,
                     x, emb, Wg, We, med, xbf, WmT, cpart);
  hipLaunchKernelGGL(k_gemm, dim3(512),  dim3(256), 0, stream,
                     WmT, xbf, med, cpart, out);
}

// Round 11
// 141.174 us; speedup vs baseline: 1.5030x; 1.0007x over previous
//
#include <hip/hip_runtime.h>

typedef unsigned int u32;
typedef unsigned short u16;
typedef float f32x4 __attribute__((ext_vector_type(4)));
typedef short s16x8 __attribute__((ext_vector_type(8)));

#define Bn 512
#define Sn 512
#define Cn 32
#define Dn 512

// ---------- helpers ----------
__device__ __forceinline__ u32 f2bf(float f) {           // fp32 -> bf16 bits, RNE
  u32 u = __float_as_uint(f);
  return (u + 0x7FFFu + ((u >> 16) & 1u)) >> 16;
}
__device__ __forceinline__ float bfval(u32 bits) { return __uint_as_float(bits << 16); }
__device__ __forceinline__ float keyToFloat(u32 k) {     // inverse of order-preserving map
  u32 u = (k & 0x80000000u) ? (k ^ 0x80000000u) : ~k;
  return __uint_as_float(u);
}
// async 16B global->LDS (LDS side must be wave-uniform base + lane*16)
__device__ __forceinline__ void gl2lds16(const void* g, void* l) {
  __builtin_amdgcn_global_load_lds(
      (const __attribute__((address_space(1))) u32*)g,
      (__attribute__((address_space(3))) u32*)l, 16, 0, 0);
}

// ---------- kernel 1: fused prep (blocks 0..1023) + wmix/gates/colsum (blocks 1024..1087)
// prep: exact median per (b,c) via ballot bisection + write xbf[b*32+v][s] bf16
// wmix: WmixT[d][s] = bf16(g1*We[e1][s][d] + g2*We[e2][s][d]), partial colsums
__global__ __launch_bounds__(256) void k_pw(const float* __restrict__ x,
                                            const float* __restrict__ emb,
                                            const float* __restrict__ Wg,
                                            const float* __restrict__ We,
                                            float* __restrict__ med,
                                            u16* __restrict__ xbf,
                                            u16* __restrict__ WmT,
                                            float* __restrict__ cpart) {
  __shared__ float buf[512][17];             // prep view; wmix aliases first 16.6 KB
  __shared__ float ed[8];
  int blk = blockIdx.x;
  int t = threadIdx.x;

  if (blk < 1024) {
    // ================= prep path =================
    int b = blk >> 1, half = blk & 1;
    int vbase = half * 16;
    int w = t >> 6, l = t & 63;
    const float4* xb4 = (const float4*)(x + (size_t)b * Sn * Cn);
    // phase 1: load 512 s x 16 v, all loads issued back-to-back
    float4 f[8];
#pragma unroll
    for (int i = 0; i < 8; ++i)
      f[i] = xb4[((t >> 2) + i * 64) * 8 + half * 4 + (t & 3)];
#pragma unroll
    for (int i = 0; i < 8; ++i) {
      int s = (t >> 2) + i * 64, c0 = (t & 3) * 4;
      buf[s][c0 + 0] = f[i].x; buf[s][c0 + 1] = f[i].y;
      buf[s][c0 + 2] = f[i].z; buf[s][c0 + 3] = f[i].w;
    }
    __syncthreads();
    // phase 2: per-wave keys for columns w*4..w*4+3
    u32 K[4][8];
#pragma unroll
    for (int cc = 0; cc < 4; ++cc)
#pragma unroll
      for (int j = 0; j < 8; ++j) {
        u32 u = __float_as_uint(buf[j * 64 + l][w * 4 + cc]);
        K[cc][j] = (u >> 31) ? ~u : (u | 0x80000000u);
      }
    // phase 3: transposed bf16 write (overlaps bisection's ALU)
    {
      int vl = t >> 4, sb = (t & 15) * 32;
      u16* orow = xbf + ((size_t)(b * 32 + vbase + vl)) * Sn;
#pragma unroll
      for (int cq = 0; cq < 4; ++cq) {
        int cp = (cq + (t & 15)) & 3;        // chunk rotation vs bank conflicts
        u32 pk[4];
#pragma unroll
        for (int jj = 0; jj < 4; ++jj) {
          u32 lo = f2bf(buf[sb + cp * 8 + jj * 2][vl]);
          u32 hi = f2bf(buf[sb + cp * 8 + jj * 2 + 1][vl]);
          pk[jj] = lo | (hi << 16);
        }
        *(uint4*)(orow + sb + cp * 8) = *(uint4*)pk;
      }
    }
    // phase 4: bisection for rank-255/256 mean
    int base = b * 32 + vbase + w * 4;
#pragma unroll
    for (int cc = 0; cc < 4; ++cc) {
      u32 a1 = 0;
#pragma unroll
      for (int bit = 31; bit >= 0; --bit) {
        u32 cand = a1 | (1u << bit);
        int c = 0;
#pragma unroll
        for (int j = 0; j < 8; ++j) c += __popcll(__ballot(K[cc][j] < cand));
        if (c <= 255) a1 = cand;
      }
      int cle = 0;
#pragma unroll
      for (int j = 0; j < 8; ++j) cle += __popcll(__ballot(K[cc][j] <= a1));
      u32 a2;
      if (cle >= 257) {
        a2 = a1;
      } else {
        u32 mn = 0xFFFFFFFFu;
#pragma unroll
        for (int j = 0; j < 8; ++j) {
          u32 k2 = K[cc][j];
          if (k2 > a1 && k2 < mn) mn = k2;
        }
        mn = min(mn, (u32)__shfl_xor((int)mn, 1, 64));
        mn = min(mn, (u32)__shfl_xor((int)mn, 2, 64));
        mn = min(mn, (u32)__shfl_xor((int)mn, 4, 64));
        mn = min(mn, (u32)__shfl_xor((int)mn, 8, 64));
        mn = min(mn, (u32)__shfl_xor((int)mn, 16, 64));
        mn = min(mn, (u32)__shfl_xor((int)mn, 32, 64));
        a2 = mn;
      }
      if (l == 0) med[base + cc] = 0.5f * (keyToFloat(a1) + keyToFloat(a2));
    }
  } else {
    // ================= wmix path =================
    float (*tile)[65] = (float(*)[65])&buf[0][0];   // 64x65 alias
    int bi2 = blk - 1024;                    // 64 blocks: 8 s-tiles x 8 d-tiles
    int si = bi2 & 7, sb = si * 64, db = (bi2 >> 3) * 64;
    // gates: redundant per block
    if (t < 8) {
      float s = 0.f;
#pragma unroll
      for (int j = 0; j < 32; ++j) s += emb[t * 32 + j] * Wg[Dn + j];
      ed[t] = s;
    }
    __syncthreads();
    int i1 = 0;
#pragma unroll
    for (int e = 1; e < 8; ++e) if (ed[e] > ed[i1]) i1 = e;
    int i2 = (i1 == 0) ? 1 : 0;
#pragma unroll
    for (int e = 0; e < 8; ++e) if (e != i1 && ed[e] > ed[i2]) i2 = e;
    float aa = ed[i1], bb = ed[i2];
    float m = fmaxf(aa, bb);
    float ea = __expf(aa - m), eb = __expf(bb - m);
    float inv = 1.f / (ea + eb);
    float g1 = ea * inv, g2 = eb * inv;
    const float* W1 = We + (size_t)i1 * Sn * Dn;
    const float* W2 = We + (size_t)i2 * Sn * Dn;
#pragma unroll
    for (int i = 0; i < 16; ++i) {
      int idx = t + i * 256;
      int sl = idx >> 6, dl = idx & 63;
      int g = (sb + sl) * Dn + db + dl;
      tile[sl][dl] = g1 * W1[g] + g2 * W2[g];
    }
    __syncthreads();
#pragma unroll
    for (int i = 0; i < 16; ++i) {
      int idx = t + i * 256;
      int dl = idx >> 6, sl = idx & 63;
      WmT[(size_t)(db + dl) * Sn + sb + sl] = (u16)f2bf(tile[sl][dl]);
    }
    // partial colsum over this s-tile: 4 threads per d
    {
      int dl = t >> 2, part = t & 3;
      float s = 0.f;
#pragma unroll
      for (int j = 0; j < 16; ++j)
        s += bfval(f2bf(tile[part * 16 + j][dl]));
      s += __shfl_xor(s, 1, 64);
      s += __shfl_xor(s, 2, 64);
      if (part == 0) cpart[si * 512 + db + dl] = s;
    }
  }
}

// ---------- kernel 2: GEMM  out[b][d][v] = sum_s WmT[d][s]*xbf[b*32+v][s] - med*colsum ----
// M=512 (d), N=16384 (b*32+v), K=512 (s). 128x128 tiles, BK=64, 4 waves.
__global__ __launch_bounds__(256) void k_gemm(const u16* __restrict__ WmT,
                                              const u16* __restrict__ xbf,
                                              const float* __restrict__ med,
                                              const float* __restrict__ cpart,
                                              float* __restrict__ out) {
  __shared__ __align__(16) u16 As[128 * 64]; // [m][k], 128B rows, 16B chunks XOR-swizzled
  __shared__ __align__(16) u16 Bs[128 * 64]; // [n][k], same
  __shared__ float csum[512];
  int bi = blockIdx.x;
  int mb = bi & 3, nb = bi >> 2;             // nb-major: consecutive blocks share B rows
  int t = threadIdx.x, w = t >> 6, l = t & 63;
  int mh = (w & 1) * 64, nh = (w >> 1) * 64;
  int lane16 = l & 15, q = l >> 4;
  // reduce colsum partials into LDS (visible after first in-loop barrier)
#pragma unroll
  for (int d = t; d < 512; d += 256) {
    float s = 0.f;
#pragma unroll
    for (int j = 0; j < 8; ++j) s += cpart[j * 512 + d];
    csum[d] = s;
  }
  f32x4 acc[4][4] = {};
  int r0 = t >> 3, c = t & 7;
  const u16* Ab = WmT + (size_t)(mb * 128) * Sn;
  const u16* Bb = xbf + (size_t)(nb * 128) * Sn;
#pragma unroll 1
  for (int ch = 0; ch < 8; ++ch) {
    int k0 = ch * 64;
    // stage A and B: 4+4 async 16B loads per thread, XOR swizzle on GLOBAL chunk
#pragma unroll
    for (int i = 0; i < 4; ++i) {
      int r = r0 + i * 32;
      int gc = c ^ (r & 7);
      gl2lds16(Ab + (size_t)r * Sn + k0 + gc * 8, (char*)As + t * 16 + i * 4096);
      gl2lds16(Bb + (size_t)r * Sn + k0 + gc * 8, (char*)Bs + t * 16 + i * 4096);
    }
    __syncthreads();
#pragma unroll
    for (int kk = 0; kk < 2; ++kk) {
      s16x8 af[4], bf[4];
#pragma unroll
      for (int mt = 0; mt < 4; ++mt) {
        int m = mh + mt * 16 + lane16;
        int cs = (kk * 4 + q) ^ (m & 7);
        af[mt] = *(const s16x8*)(As + m * 64 + cs * 8);
      }
#pragma unroll
      for (int nt = 0; nt < 4; ++nt) {
        int n = nh + nt * 16 + lane16;
        int cs = (kk * 4 + q) ^ (n & 7);
        bf[nt] = *(const s16x8*)(Bs + n * 64 + cs * 8);
      }
#pragma unroll
      for (int mt = 0; mt < 4; ++mt)
#pragma unroll
        for (int nt = 0; nt < 4; ++nt)
          acc[mt][nt] = __builtin_amdgcn_mfma_f32_16x16x32_bf16(af[mt], bf[nt], acc[mt][nt], 0, 0, 0);
    }
    __syncthreads();
  }
  // epilogue: subtract med[n]*colsum[d]
#pragma unroll
  for (int nt = 0; nt < 4; ++nt) {
    int n = nb * 128 + nh + nt * 16 + lane16;
    int b = n >> 5, v = n & 31;
    float mv = med[n];
    float* obase = out + (size_t)b * (Dn * Cn) + v;
#pragma unroll
    for (int mt = 0; mt < 4; ++mt) {
      int d0 = mb * 128 + mh + mt * 16 + q * 4;
#pragma unroll
      for (int r = 0; r < 4; ++r)
        obase[(size_t)(d0 + r) * Cn] = acc[mt][nt][r] - mv * csum[d0 + r];
    }
  }
}

extern "C" void kernel_launch(void* const* d_in, const int* in_sizes, int n_in,
                              void* d_out, int out_size, void* d_ws, size_t ws_size,
                              hipStream_t stream) {
  const float* x   = (const float*)d_in[0];
  const float* emb = (const float*)d_in[3];
  const float* Wg  = (const float*)d_in[4];
  const float* We  = (const float*)d_in[6];
  float* out = (float*)d_out;
  char* ws = (char*)d_ws;
  float* med   = (float*)(ws);                         // 64 KB
  float* cpart = (float*)(ws + 65536);                 // 16 KB
  u16*   WmT   = (u16*)(ws + 65536 + 16384);           // 512 KB
  u16*   xbf   = (u16*)(ws + 65536 + 16384 + 524288);  // 16.8 MB

  hipLaunchKernelGGL(k_pw,   dim3(1088), dim3(256), 0, stream,
                     x, emb, Wg, We, med, xbf, WmT, cpart);
  hipLaunchKernelGGL(k_gemm, dim3(512),  dim3(256), 0, stream,
                     WmT, xbf, med, cpart, out);
}